// Round 5
// baseline (857.200 us; speedup 1.0000x reference)
//
#include <hip/hip_runtime.h>

#define NTOK 1024
#define HDIM 2880
#define IDIM 2880
#define NEXP 8
#define BK 64
#define NT (HDIM / BK)  // 45

typedef __attribute__((ext_vector_type(4))) float fx4;
typedef __attribute__((ext_vector_type(8))) short sx8;
typedef __attribute__((ext_vector_type(4))) unsigned short usx4;
typedef __attribute__((ext_vector_type(8))) unsigned short usx8;

typedef const __attribute__((address_space(1))) void* gas_p;
typedef __attribute__((address_space(3))) void* las_p;

__device__ __forceinline__ unsigned short f2bf(float f) {
  unsigned u = __builtin_bit_cast(unsigned, f);
  u += 0x7fffu + ((u >> 16) & 1u);
  return (unsigned short)(u >> 16);
}
__device__ __forceinline__ usx8 cvt8(fx4 a, fx4 b) {
  usx8 u = {f2bf(a.x), f2bf(a.y), f2bf(a.z), f2bf(a.w),
            f2bf(b.x), f2bf(b.y), f2bf(b.z), f2bf(b.w)};
  return u;
}

__global__ __launch_bounds__(256) void init_out_k(const float* __restrict__ x,
                                                  float* __restrict__ out) {
  int i = blockIdx.x * 256 + threadIdx.x;
  ((fx4*)out)[i] = ((const fx4*)x)[i];
}

__global__ __launch_bounds__(256) void rms_router_k(
    const float* __restrict__ x, const float* __restrict__ norm_w,
    const float* __restrict__ gate_w, const float* __restrict__ gate_b,
    unsigned short* __restrict__ t_bf, int* __restrict__ cnt,
    int* __restrict__ tok, float* __restrict__ wgt) {
  const int n = blockIdx.x;
  const int tid = threadIdx.x;
  const int wid = tid >> 6, lane = tid & 63;
  const float* xr = x + (size_t)n * HDIM;

  float ss = 0.f;
  for (int h = tid; h < HDIM; h += 256) { float v = xr[h]; ss += v * v; }
  #pragma unroll
  for (int o = 32; o > 0; o >>= 1) ss += __shfl_down(ss, o);
  __shared__ float sred[4];
  if (lane == 0) sred[wid] = ss;
  __syncthreads();
  const float rstd =
      rsqrtf((sred[0] + sred[1] + sred[2] + sred[3]) * (1.0f / HDIM) + 1e-5f);

  float p[NEXP];
  #pragma unroll
  for (int e = 0; e < NEXP; e++) p[e] = 0.f;
  for (int h = tid; h < HDIM; h += 256) {
    float xv = xr[h] * norm_w[h];
    t_bf[(size_t)n * HDIM + h] = f2bf(xv * rstd);
    #pragma unroll
    for (int e = 0; e < NEXP; e++) p[e] += xv * gate_w[e * HDIM + h];
  }
  __shared__ float pls[4][NEXP];
  #pragma unroll
  for (int e = 0; e < NEXP; e++) {
    float v = p[e];
    #pragma unroll
    for (int o = 32; o > 0; o >>= 1) v += __shfl_down(v, o);
    if (lane == 0) pls[wid][e] = v;
  }
  __syncthreads();
  if (tid == 0) {
    float lg[NEXP];
    #pragma unroll
    for (int e = 0; e < NEXP; e++)
      lg[e] = (pls[0][e] + pls[1][e] + pls[2][e] + pls[3][e]) * rstd + gate_b[e];
    unsigned used = 0;
    float val[4];
    int idx[4];
    for (int k = 0; k < 4; k++) {
      float best = -1e30f;
      int bi = 0;
      for (int e = 0; e < NEXP; e++)
        if (!((used >> e) & 1u) && lg[e] > best) { best = lg[e]; bi = e; }
      used |= 1u << bi;
      val[k] = best;
      idx[k] = bi;
    }
    float sum = 0.f, w[4];
    for (int k = 0; k < 4; k++) { w[k] = expf(val[k] - val[0]); sum += w[k]; }
    for (int k = 0; k < 4; k++) {
      int e = idx[k];
      int slot = atomicAdd(&cnt[e], 1);
      tok[e * NTOK + slot] = n;
      wgt[e * NTOK + slot] = w[k] / sum;
    }
  }
}

// GEMM1: BM=128 x (64 glu + 64 lin), BK=64, 4 waves (2m x 2n).
// Single LDS buffer; register-double-buffered staging; XOR chunk^(row&7)
// swizzle on A (pre-swizzled gather source) and B (swizzled write+read).
__global__ __launch_bounds__(256) void gemm1_k(
    const unsigned short* __restrict__ t_bf,
    const float* __restrict__ w_gate_up, const float* __restrict__ b_gate_up,
    const int* __restrict__ cnt, const int* __restrict__ tok,
    unsigned short* __restrict__ act_bf) {
  const int e = blockIdx.y;
  const int ce = cnt[e];
  const int m0 = blockIdx.z * 128;
  if (m0 >= ce) return;
  const int c0 = blockIdx.x * 64;
  const int tid = threadIdx.x, lane = tid & 63, wid = tid >> 6;
  const int fr = lane & 15, fq = lane >> 4;
  const int wm = wid >> 1, wn = wid & 1;

  __shared__ unsigned short Ash[128 * 64];  // 16 KB, rows x 64 shorts
  __shared__ unsigned short Bsh[128 * 64];  // 16 KB, rows 0-63 G, 64-127 L

  const fx4 FZ = {0.f, 0.f, 0.f, 0.f};
  fx4 accG[4][2], accL[4][2];
  #pragma unroll
  for (int m = 0; m < 4; m++)
    #pragma unroll
    for (int n = 0; n < 2; n++) { accG[m][n] = FZ; accL[m][n] = FZ; }

  // A gather: wave stages rows wid*32+j*8+(lane>>3); source chunk pre-swizzled
  const unsigned short* gA[4];
  #pragma unroll
  for (int j = 0; j < 4; ++j) {
    int R = m0 + wid * 32 + j * 8 + (lane >> 3);
    int rc = R < ce ? R : ce - 1;
    gA[j] = t_bf + (size_t)tok[e * NTOK + rc] * HDIM +
            ((lane & 7) ^ ((lane >> 3) & 7)) * 8;
  }
  // B: 128 rows x 8 float8-pairs; thread covers pair p = tid + 256*j
  const float* wb = w_gate_up + (size_t)e * (2 * IDIM) * HDIM;
  const float* srcB[4];
  int bro[4], bfp[4];
  #pragma unroll
  for (int j = 0; j < 4; ++j) {
    int p = tid + 256 * j;
    int row = p >> 3, fp = p & 7;
    bro[j] = row;
    bfp[j] = fp;
    int wrow = row < 64 ? (c0 + row) : (IDIM + c0 + row - 64);
    srcB[j] = wb + (size_t)wrow * HDIM + fp * 8;
  }

  // stage tile 0
  {
    fx4 r0[8];
    #pragma unroll
    for (int j = 0; j < 4; ++j) {
      r0[2 * j] = *(const fx4*)(srcB[j]);
      r0[2 * j + 1] = *(const fx4*)(srcB[j] + 4);
    }
    #pragma unroll
    for (int j = 0; j < 4; ++j)
      __builtin_amdgcn_global_load_lds((gas_p)gA[j],
                                       (las_p)&Ash[(wid * 32 + j * 8) * 64], 16,
                                       0, 0);
    #pragma unroll
    for (int j = 0; j < 4; ++j)
      *(usx8*)&Bsh[bro[j] * 64 + ((bfp[j] ^ (bro[j] & 7)) * 8)] =
          cvt8(r0[2 * j], r0[2 * j + 1]);
  }
  __syncthreads();

  for (int t = 0; t < NT; ++t) {
    const int kn = (t + 1 < NT) ? (t + 1) * BK : 0;
    // issue next B loads early (long HBM latency hides under compute)
    fx4 nB[8];
    #pragma unroll
    for (int j = 0; j < 4; ++j) {
      nB[2 * j] = *(const fx4*)(srcB[j] + kn);
      nB[2 * j + 1] = *(const fx4*)(srcB[j] + kn + 4);
    }
    #pragma unroll
    for (int ks = 0; ks < 2; ++ks) {
      sx8 aF[4];
      #pragma unroll
      for (int m = 0; m < 4; ++m)
        aF[m] = *(const sx8*)&Ash[(wm * 64 + m * 16 + fr) * 64 +
                                  (((ks * 4 + fq) ^ (fr & 7)) * 8)];
      #pragma unroll
      for (int n = 0; n < 2; ++n) {
        sx8 bG = *(const sx8*)&Bsh[(wn * 32 + n * 16 + fr) * 64 +
                                   (((ks * 4 + fq) ^ (fr & 7)) * 8)];
        sx8 bL = *(const sx8*)&Bsh[(64 + wn * 32 + n * 16 + fr) * 64 +
                                   (((ks * 4 + fq) ^ (fr & 7)) * 8)];
        #pragma unroll
        for (int m = 0; m < 4; ++m) {
          accG[m][n] = __builtin_amdgcn_mfma_f32_16x16x32_bf16(aF[m], bG,
                                                               accG[m][n], 0, 0, 0);
          accL[m][n] = __builtin_amdgcn_mfma_f32_16x16x32_bf16(aF[m], bL,
                                                               accL[m][n], 0, 0, 0);
        }
      }
    }
    __syncthreads();  // all waves done reading tile t
    if (t + 1 < NT) {
      #pragma unroll
      for (int j = 0; j < 4; ++j)
        __builtin_amdgcn_global_load_lds((gas_p)(gA[j] + kn),
                                         (las_p)&Ash[(wid * 32 + j * 8) * 64],
                                         16, 0, 0);
      #pragma unroll
      for (int j = 0; j < 4; ++j)
        *(usx8*)&Bsh[bro[j] * 64 + ((bfp[j] ^ (bro[j] & 7)) * 8)] =
            cvt8(nB[2 * j], nB[2 * j + 1]);
      __syncthreads();  // tile t+1 ready
    }
  }

  #pragma unroll
  for (int n = 0; n < 2; ++n) {
    const int col = c0 + wn * 32 + n * 16 + fr;
    const float bg = b_gate_up[e * (2 * IDIM) + col];
    const float bl = b_gate_up[e * (2 * IDIM) + IDIM + col];
    #pragma unroll
    for (int m = 0; m < 4; ++m) {
      #pragma unroll
      for (int r = 0; r < 4; ++r) {
        int slot = m0 + wm * 64 + m * 16 + fq * 4 + r;
        if (slot < ce) {
          float g = accG[m][n][r] + bg;
          float l = accL[m][n][r] + bl;
          float a = g * (1.0f / (1.0f + __expf(-1.702f * g))) * (l + 1.0f);
          act_bf[((size_t)e * NTOK + slot) * IDIM + col] = f2bf(a);
        }
      }
    }
  }
}

// GEMM2: BM=128 x 96 cols, BK=64, 4 waves (2m x 2n, 48 cols/wave).
__global__ __launch_bounds__(256) void gemm2_k(
    const unsigned short* __restrict__ act_bf, const float* __restrict__ w_down,
    const float* __restrict__ b_down, const int* __restrict__ cnt,
    const int* __restrict__ tok, const float* __restrict__ wgt,
    float* __restrict__ out) {
  const int e = blockIdx.y;
  const int ce = cnt[e];
  const int m0 = blockIdx.z * 128;
  if (m0 >= ce) return;
  const int c0 = blockIdx.x * 96;
  const int tid = threadIdx.x, lane = tid & 63, wid = tid >> 6;
  const int fr = lane & 15, fq = lane >> 4;
  const int wm = wid >> 1, wn = wid & 1;

  __shared__ unsigned short Ash[128 * 64];  // 16 KB
  __shared__ unsigned short Bsh[96 * 64];   // 12 KB

  const fx4 FZ = {0.f, 0.f, 0.f, 0.f};
  fx4 acc[4][3];
  #pragma unroll
  for (int m = 0; m < 4; m++)
    #pragma unroll
    for (int n = 0; n < 3; n++) acc[m][n] = FZ;

  const unsigned short* gA[4];
  #pragma unroll
  for (int j = 0; j < 4; ++j) {
    int R = m0 + wid * 32 + j * 8 + (lane >> 3);
    int rc = R < ce ? R : ce - 1;
    gA[j] = act_bf + ((size_t)e * NTOK + rc) * IDIM +
            ((lane & 7) ^ ((lane >> 3) & 7)) * 8;
  }
  const float* wb = w_down + (size_t)e * HDIM * IDIM;
  const float* srcB[3];
  int bro[3], bfp[3];
  #pragma unroll
  for (int j = 0; j < 3; ++j) {
    int p = tid + 256 * j;  // 768 pairs = 96 rows x 8
    int row = p >> 3, fp = p & 7;
    bro[j] = row;
    bfp[j] = fp;
    srcB[j] = wb + (size_t)(c0 + row) * IDIM + fp * 8;
  }

  {
    fx4 r0[6];
    #pragma unroll
    for (int j = 0; j < 3; ++j) {
      r0[2 * j] = *(const fx4*)(srcB[j]);
      r0[2 * j + 1] = *(const fx4*)(srcB[j] + 4);
    }
    #pragma unroll
    for (int j = 0; j < 4; ++j)
      __builtin_amdgcn_global_load_lds((gas_p)gA[j],
                                       (las_p)&Ash[(wid * 32 + j * 8) * 64], 16,
                                       0, 0);
    #pragma unroll
    for (int j = 0; j < 3; ++j)
      *(usx8*)&Bsh[bro[j] * 64 + ((bfp[j] ^ (bro[j] & 7)) * 8)] =
          cvt8(r0[2 * j], r0[2 * j + 1]);
  }
  __syncthreads();

  for (int t = 0; t < NT; ++t) {
    const int kn = (t + 1 < NT) ? (t + 1) * BK : 0;
    fx4 nB[6];
    #pragma unroll
    for (int j = 0; j < 3; ++j) {
      nB[2 * j] = *(const fx4*)(srcB[j] + kn);
      nB[2 * j + 1] = *(const fx4*)(srcB[j] + kn + 4);
    }
    #pragma unroll
    for (int ks = 0; ks < 2; ++ks) {
      sx8 aF[4];
      #pragma unroll
      for (int m = 0; m < 4; ++m)
        aF[m] = *(const sx8*)&Ash[(wm * 64 + m * 16 + fr) * 64 +
                                  (((ks * 4 + fq) ^ (fr & 7)) * 8)];
      #pragma unroll
      for (int n = 0; n < 3; ++n) {
        sx8 b0 = *(const sx8*)&Bsh[(wn * 48 + n * 16 + fr) * 64 +
                                   (((ks * 4 + fq) ^ (fr & 7)) * 8)];
        #pragma unroll
        for (int m = 0; m < 4; ++m)
          acc[m][n] = __builtin_amdgcn_mfma_f32_16x16x32_bf16(aF[m], b0,
                                                              acc[m][n], 0, 0, 0);
      }
    }
    __syncthreads();
    if (t + 1 < NT) {
      #pragma unroll
      for (int j = 0; j < 4; ++j)
        __builtin_amdgcn_global_load_lds((gas_p)(gA[j] + kn),
                                         (las_p)&Ash[(wid * 32 + j * 8) * 64],
                                         16, 0, 0);
      #pragma unroll
      for (int j = 0; j < 3; ++j)
        *(usx8*)&Bsh[bro[j] * 64 + ((bfp[j] ^ (bro[j] & 7)) * 8)] =
            cvt8(nB[2 * j], nB[2 * j + 1]);
      __syncthreads();
    }
  }

  #pragma unroll
  for (int n = 0; n < 3; ++n) {
    const int col = c0 + wn * 48 + n * 16 + fr;
    const float bias = b_down[e * HDIM + col];
    #pragma unroll
    for (int m = 0; m < 4; ++m) {
      #pragma unroll
      for (int r = 0; r < 4; ++r) {
        int slot = m0 + wm * 64 + m * 16 + fq * 4 + r;
        if (slot < ce) {
          int token = tok[e * NTOK + slot];
          float w = wgt[e * NTOK + slot];
          atomicAdd(&out[(size_t)token * HDIM + col], w * (acc[m][n][r] + bias));
        }
      }
    }
  }
}

extern "C" void kernel_launch(void* const* d_in, const int* in_sizes, int n_in,
                              void* d_out, int out_size, void* d_ws,
                              size_t ws_size, hipStream_t stream) {
  const float* x = (const float*)d_in[0];
  const float* norm_w = (const float*)d_in[1];
  const float* gate_w = (const float*)d_in[2];
  const float* gate_b = (const float*)d_in[3];
  const float* w_gate_up = (const float*)d_in[4];
  const float* b_gate_up = (const float*)d_in[5];
  const float* w_down = (const float*)d_in[6];
  const float* b_down = (const float*)d_in[7];
  float* out = (float*)d_out;

  char* ws = (char*)d_ws;
  unsigned short* t_bf = (unsigned short*)ws;
  ws += (size_t)NTOK * HDIM * 2;
  unsigned short* act_bf = (unsigned short*)ws;
  ws += (size_t)NEXP * NTOK * IDIM * 2;
  int* cnt = (int*)ws;
  ws += 256;
  int* tok = (int*)ws;
  ws += (size_t)NEXP * NTOK * 4;
  float* wgt = (float*)ws;
  ws += (size_t)NEXP * NTOK * 4;

  hipMemsetAsync(cnt, 0, NEXP * sizeof(int), stream);
  init_out_k<<<2880, 256, 0, stream>>>(x, out);
  rms_router_k<<<NTOK, 256, 0, stream>>>(x, norm_w, gate_w, gate_b, t_bf, cnt,
                                         tok, wgt);
  gemm1_k<<<dim3(45, NEXP, 8), 256, 0, stream>>>(t_bf, w_gate_up, b_gate_up,
                                                 cnt, tok, act_bf);
  gemm2_k<<<dim3(30, NEXP, 8), 256, 0, stream>>>(act_bf, w_down, b_down, cnt,
                                                 tok, wgt, out);
}

// Round 6
// 720.646 us; speedup vs baseline: 1.1895x; 1.1895x over previous
//
#include <hip/hip_runtime.h>

#define NTOK 1024
#define HDIM 2880
#define IDIM 2880
#define NEXP 8
#define BK 64
#define NT (HDIM / BK)  // 45

typedef __attribute__((ext_vector_type(4))) float fx4;
typedef __attribute__((ext_vector_type(8))) short sx8;
typedef __attribute__((ext_vector_type(8))) unsigned short usx8;

typedef const __attribute__((address_space(1))) void* gas_p;
typedef __attribute__((address_space(3))) void* las_p;

__device__ __forceinline__ unsigned short f2bf(float f) {
  unsigned u = __builtin_bit_cast(unsigned, f);
  u += 0x7fffu + ((u >> 16) & 1u);
  return (unsigned short)(u >> 16);
}
__device__ __forceinline__ usx8 cvt8(fx4 a, fx4 b) {
  usx8 u = {f2bf(a.x), f2bf(a.y), f2bf(a.z), f2bf(a.w),
            f2bf(b.x), f2bf(b.y), f2bf(b.z), f2bf(b.w)};
  return u;
}

__global__ __launch_bounds__(256) void init_out_k(const float* __restrict__ x,
                                                  float* __restrict__ out) {
  int i = blockIdx.x * 256 + threadIdx.x;
  ((fx4*)out)[i] = ((const fx4*)x)[i];
}

__global__ __launch_bounds__(256) void rms_router_k(
    const float* __restrict__ x, const float* __restrict__ norm_w,
    const float* __restrict__ gate_w, const float* __restrict__ gate_b,
    unsigned short* __restrict__ t_bf, int* __restrict__ cnt,
    int* __restrict__ tok, float* __restrict__ wgt) {
  const int n = blockIdx.x;
  const int tid = threadIdx.x;
  const int wid = tid >> 6, lane = tid & 63;
  const float* xr = x + (size_t)n * HDIM;

  float ss = 0.f;
  for (int h = tid; h < HDIM; h += 256) { float v = xr[h]; ss += v * v; }
  #pragma unroll
  for (int o = 32; o > 0; o >>= 1) ss += __shfl_down(ss, o);
  __shared__ float sred[4];
  if (lane == 0) sred[wid] = ss;
  __syncthreads();
  const float rstd =
      rsqrtf((sred[0] + sred[1] + sred[2] + sred[3]) * (1.0f / HDIM) + 1e-5f);

  float p[NEXP];
  #pragma unroll
  for (int e = 0; e < NEXP; e++) p[e] = 0.f;
  for (int h = tid; h < HDIM; h += 256) {
    float xv = xr[h] * norm_w[h];
    t_bf[(size_t)n * HDIM + h] = f2bf(xv * rstd);
    #pragma unroll
    for (int e = 0; e < NEXP; e++) p[e] += xv * gate_w[e * HDIM + h];
  }
  __shared__ float pls[4][NEXP];
  #pragma unroll
  for (int e = 0; e < NEXP; e++) {
    float v = p[e];
    #pragma unroll
    for (int o = 32; o > 0; o >>= 1) v += __shfl_down(v, o);
    if (lane == 0) pls[wid][e] = v;
  }
  __syncthreads();
  if (tid == 0) {
    float lg[NEXP];
    #pragma unroll
    for (int e = 0; e < NEXP; e++)
      lg[e] = (pls[0][e] + pls[1][e] + pls[2][e] + pls[3][e]) * rstd + gate_b[e];
    unsigned used = 0;
    float val[4];
    int idx[4];
    for (int k = 0; k < 4; k++) {
      float best = -1e30f;
      int bi = 0;
      for (int e = 0; e < NEXP; e++)
        if (!((used >> e) & 1u) && lg[e] > best) { best = lg[e]; bi = e; }
      used |= 1u << bi;
      val[k] = best;
      idx[k] = bi;
    }
    float sum = 0.f, w[4];
    for (int k = 0; k < 4; k++) { w[k] = expf(val[k] - val[0]); sum += w[k]; }
    for (int k = 0; k < 4; k++) {
      int e = idx[k];
      int slot = atomicAdd(&cnt[e], 1);
      tok[e * NTOK + slot] = n;
      wgt[e * NTOK + slot] = w[k] / sum;
    }
  }
}

// GEMM1: block = 256 tokens x (96 G + 96 L) cols, BK=64, 8 waves (4m x 2n),
// dbuf LDS 112 KB (1 block/CU). A: global_load_lds + XOR-swizzled source.
// B: reg-staged fp32->bf16, XOR-swizzled write. One barrier per K-tile;
// t+1 staging issued before compute of t.
__global__ __launch_bounds__(512) void gemm1_k(
    const unsigned short* __restrict__ t_bf,
    const float* __restrict__ w_gate_up, const float* __restrict__ b_gate_up,
    const int* __restrict__ cnt, const int* __restrict__ tok,
    unsigned short* __restrict__ act_bf) {
  const int e = blockIdx.y;
  const int ce = cnt[e];
  const int m0 = blockIdx.z * 256;
  if (m0 >= ce) return;
  const int c0 = blockIdx.x * 96;
  const int tid = threadIdx.x, lane = tid & 63, wid = tid >> 6;
  const int fr = lane & 15, fq = lane >> 4;
  const int wm = wid >> 1, wc = (wid & 1) * 48;

  __shared__ unsigned short Ash[2][256 * 64];  // 64 KB
  __shared__ unsigned short Bsh[2][192 * 64];  // 48 KB (rows 0-95 G, 96-191 L)

  const fx4 FZ = {0.f, 0.f, 0.f, 0.f};
  fx4 accG[4][3], accL[4][3];
  #pragma unroll
  for (int m = 0; m < 4; m++)
    #pragma unroll
    for (int n = 0; n < 3; n++) { accG[m][n] = FZ; accL[m][n] = FZ; }

  // A gather: instr j stages rows [wid*32 + j*8, +8) x 64 shorts.
  // Source chunk pre-swizzled: global chunk (lane&7)^((lane>>3)&7) -> LDS
  // lands XOR(row&7)-swizzled (round-5-verified conflict-free).
  const unsigned short* gA[4];
  #pragma unroll
  for (int j = 0; j < 4; ++j) {
    int R = m0 + wid * 32 + j * 8 + (lane >> 3);
    int rc = R < ce ? R : ce - 1;
    gA[j] = t_bf + (size_t)tok[e * NTOK + rc] * HDIM +
            ((lane & 7) ^ ((lane >> 3) & 7)) * 8;
  }
  // B: 192 rows x 8 chunks (8 floats each); thread covers flat = tid + 512*j.
  const float* wb = w_gate_up + (size_t)e * (2 * IDIM) * HDIM;
  const float* srcB[3];
  int bro[3], bch[3];
  #pragma unroll
  for (int j = 0; j < 3; ++j) {
    int flat = tid + 512 * j;
    int row = flat >> 3, ch = flat & 7;
    bro[j] = row;
    bch[j] = ch;
    int wrow = row < 96 ? (c0 + row) : (IDIM + c0 + row - 96);
    srcB[j] = wb + (size_t)wrow * HDIM + ch * 8;
  }

  #define G1_PHASE(buf, ks)                                                    \
    {                                                                          \
      sx8 aF[4], bG[3], bL[3];                                                 \
      _Pragma("unroll") for (int m = 0; m < 4; ++m) aF[m] =                    \
          *(const sx8*)&Ash[buf][(wm * 64 + m * 16 + fr) * 64 +                \
                                 ((((ks)*4 + fq) ^ (fr & 7)) * 8)];            \
      _Pragma("unroll") for (int n = 0; n < 3; ++n) {                          \
        bG[n] = *(const sx8*)&Bsh[buf][(wc + n * 16 + fr) * 64 +               \
                                       ((((ks)*4 + fq) ^ (fr & 7)) * 8)];      \
        bL[n] = *(const sx8*)&Bsh[buf][(96 + wc + n * 16 + fr) * 64 +          \
                                       ((((ks)*4 + fq) ^ (fr & 7)) * 8)];      \
      }                                                                        \
      __builtin_amdgcn_s_setprio(1);                                           \
      _Pragma("unroll") for (int n = 0; n < 3; ++n)                            \
          _Pragma("unroll") for (int m = 0; m < 4; ++m) {                      \
        accG[m][n] = __builtin_amdgcn_mfma_f32_16x16x32_bf16(aF[m], bG[n],     \
                                                             accG[m][n], 0, 0, 0); \
        accL[m][n] = __builtin_amdgcn_mfma_f32_16x16x32_bf16(aF[m], bL[n],     \
                                                             accL[m][n], 0, 0, 0); \
      }                                                                        \
      __builtin_amdgcn_s_setprio(0);                                           \
    }

  // prologue: stage tile 0
  {
    fx4 rB[6];
    #pragma unroll
    for (int j = 0; j < 3; ++j) {
      rB[2 * j] = *(const fx4*)(srcB[j]);
      rB[2 * j + 1] = *(const fx4*)(srcB[j] + 4);
    }
    #pragma unroll
    for (int j = 0; j < 4; ++j)
      __builtin_amdgcn_global_load_lds((gas_p)gA[j],
                                       (las_p)&Ash[0][(wid * 32 + j * 8) * 64],
                                       16, 0, 0);
    #pragma unroll
    for (int j = 0; j < 3; ++j)
      *(usx8*)&Bsh[0][bro[j] * 64 + ((bch[j] ^ (bro[j] & 7)) * 8)] =
          cvt8(rB[2 * j], rB[2 * j + 1]);
  }
  __syncthreads();

  int cur = 0;
  for (int t = 0; t < NT; ++t) {
    const int nxt = cur ^ 1;
    fx4 nB[6];
    if (t + 1 < NT) {
      const int kf = (t + 1) * BK;
      #pragma unroll
      for (int j = 0; j < 3; ++j) {
        nB[2 * j] = *(const fx4*)(srcB[j] + kf);
        nB[2 * j + 1] = *(const fx4*)(srcB[j] + kf + 4);
      }
      #pragma unroll
      for (int j = 0; j < 4; ++j)
        __builtin_amdgcn_global_load_lds(
            (gas_p)(gA[j] + kf), (las_p)&Ash[nxt][(wid * 32 + j * 8) * 64], 16,
            0, 0);
    }
    G1_PHASE(cur, 0);
    G1_PHASE(cur, 1);
    if (t + 1 < NT) {
      #pragma unroll
      for (int j = 0; j < 3; ++j)
        *(usx8*)&Bsh[nxt][bro[j] * 64 + ((bch[j] ^ (bro[j] & 7)) * 8)] =
            cvt8(nB[2 * j], nB[2 * j + 1]);
      __syncthreads();
      cur = nxt;
    }
  }

  #pragma unroll
  for (int n = 0; n < 3; ++n) {
    const int col = c0 + wc + n * 16 + fr;
    const float bg = b_gate_up[e * (2 * IDIM) + col];
    const float bl = b_gate_up[e * (2 * IDIM) + IDIM + col];
    #pragma unroll
    for (int m = 0; m < 4; ++m) {
      #pragma unroll
      for (int r = 0; r < 4; ++r) {
        int slot = m0 + wm * 64 + m * 16 + fq * 4 + r;
        if (slot < ce) {
          float g = accG[m][n][r] + bg;
          float l = accL[m][n][r] + bl;
          float a = g * (1.0f / (1.0f + __expf(-1.702f * g))) * (l + 1.0f);
          act_bf[((size_t)e * NTOK + slot) * IDIM + col] = f2bf(a);
        }
      }
    }
  }
}

// GEMM2: block = 256 rows x 192 cols, BK=64, 8 waves (4m x 2n), dbuf 112 KB.
__global__ __launch_bounds__(512) void gemm2_k(
    const unsigned short* __restrict__ act_bf, const float* __restrict__ w_down,
    const float* __restrict__ b_down, const int* __restrict__ cnt,
    const int* __restrict__ tok, const float* __restrict__ wgt,
    float* __restrict__ out) {
  const int e = blockIdx.y;
  const int ce = cnt[e];
  const int m0 = blockIdx.z * 256;
  if (m0 >= ce) return;
  const int c0 = blockIdx.x * 192;
  const int tid = threadIdx.x, lane = tid & 63, wid = tid >> 6;
  const int fr = lane & 15, fq = lane >> 4;
  const int wm = wid >> 1, wc = (wid & 1) * 96;

  __shared__ unsigned short Ash[2][256 * 64];  // 64 KB
  __shared__ unsigned short Bsh[2][192 * 64];  // 48 KB

  const fx4 FZ = {0.f, 0.f, 0.f, 0.f};
  fx4 acc[4][6];
  #pragma unroll
  for (int m = 0; m < 4; m++)
    #pragma unroll
    for (int n = 0; n < 6; n++) acc[m][n] = FZ;

  const unsigned short* gA[4];
  #pragma unroll
  for (int j = 0; j < 4; ++j) {
    int R = m0 + wid * 32 + j * 8 + (lane >> 3);
    int rc = R < ce ? R : ce - 1;
    gA[j] = act_bf + ((size_t)e * NTOK + rc) * IDIM +
            ((lane & 7) ^ ((lane >> 3) & 7)) * 8;
  }
  const float* wb = w_down + (size_t)e * HDIM * IDIM;
  const float* srcB[3];
  int bro[3], bch[3];
  #pragma unroll
  for (int j = 0; j < 3; ++j) {
    int flat = tid + 512 * j;
    int row = flat >> 3, ch = flat & 7;
    bro[j] = row;
    bch[j] = ch;
    srcB[j] = wb + (size_t)(c0 + row) * IDIM + ch * 8;
  }

  #define G2_PHASE(buf, ks)                                                    \
    {                                                                          \
      sx8 aF[4], bB[6];                                                        \
      _Pragma("unroll") for (int m = 0; m < 4; ++m) aF[m] =                    \
          *(const sx8*)&Ash[buf][(wm * 64 + m * 16 + fr) * 64 +                \
                                 ((((ks)*4 + fq) ^ (fr & 7)) * 8)];            \
      _Pragma("unroll") for (int n = 0; n < 6; ++n) bB[n] =                    \
          *(const sx8*)&Bsh[buf][(wc + n * 16 + fr) * 64 +                     \
                                 ((((ks)*4 + fq) ^ (fr & 7)) * 8)];            \
      __builtin_amdgcn_s_setprio(1);                                           \
      _Pragma("unroll") for (int n = 0; n < 6; ++n)                            \
          _Pragma("unroll") for (int m = 0; m < 4; ++m)                        \
              acc[m][n] = __builtin_amdgcn_mfma_f32_16x16x32_bf16(aF[m], bB[n],\
                                                                  acc[m][n], 0, 0, 0); \
      __builtin_amdgcn_s_setprio(0);                                           \
    }

  {
    fx4 rB[6];
    #pragma unroll
    for (int j = 0; j < 3; ++j) {
      rB[2 * j] = *(const fx4*)(srcB[j]);
      rB[2 * j + 1] = *(const fx4*)(srcB[j] + 4);
    }
    #pragma unroll
    for (int j = 0; j < 4; ++j)
      __builtin_amdgcn_global_load_lds((gas_p)gA[j],
                                       (las_p)&Ash[0][(wid * 32 + j * 8) * 64],
                                       16, 0, 0);
    #pragma unroll
    for (int j = 0; j < 3; ++j)
      *(usx8*)&Bsh[0][bro[j] * 64 + ((bch[j] ^ (bro[j] & 7)) * 8)] =
          cvt8(rB[2 * j], rB[2 * j + 1]);
  }
  __syncthreads();

  int cur = 0;
  for (int t = 0; t < NT; ++t) {
    const int nxt = cur ^ 1;
    fx4 nB[6];
    if (t + 1 < NT) {
      const int kf = (t + 1) * BK;
      #pragma unroll
      for (int j = 0; j < 3; ++j) {
        nB[2 * j] = *(const fx4*)(srcB[j] + kf);
        nB[2 * j + 1] = *(const fx4*)(srcB[j] + kf + 4);
      }
      #pragma unroll
      for (int j = 0; j < 4; ++j)
        __builtin_amdgcn_global_load_lds(
            (gas_p)(gA[j] + kf), (las_p)&Ash[nxt][(wid * 32 + j * 8) * 64], 16,
            0, 0);
    }
    G2_PHASE(cur, 0);
    G2_PHASE(cur, 1);
    if (t + 1 < NT) {
      #pragma unroll
      for (int j = 0; j < 3; ++j)
        *(usx8*)&Bsh[nxt][bro[j] * 64 + ((bch[j] ^ (bro[j] & 7)) * 8)] =
            cvt8(nB[2 * j], nB[2 * j + 1]);
      __syncthreads();
      cur = nxt;
    }
  }

  #pragma unroll
  for (int n = 0; n < 6; ++n) {
    const int col = c0 + wc + n * 16 + fr;
    const float bias = b_down[e * HDIM + col];
    #pragma unroll
    for (int m = 0; m < 4; ++m) {
      #pragma unroll
      for (int r = 0; r < 4; ++r) {
        int slot = m0 + wm * 64 + m * 16 + fq * 4 + r;
        if (slot < ce) {
          int token = tok[e * NTOK + slot];
          float w = wgt[e * NTOK + slot];
          atomicAdd(&out[(size_t)token * HDIM + col], w * (acc[m][n][r] + bias));
        }
      }
    }
  }
}

extern "C" void kernel_launch(void* const* d_in, const int* in_sizes, int n_in,
                              void* d_out, int out_size, void* d_ws,
                              size_t ws_size, hipStream_t stream) {
  const float* x = (const float*)d_in[0];
  const float* norm_w = (const float*)d_in[1];
  const float* gate_w = (const float*)d_in[2];
  const float* gate_b = (const float*)d_in[3];
  const float* w_gate_up = (const float*)d_in[4];
  const float* b_gate_up = (const float*)d_in[5];
  const float* w_down = (const float*)d_in[6];
  const float* b_down = (const float*)d_in[7];
  float* out = (float*)d_out;

  char* ws = (char*)d_ws;
  unsigned short* t_bf = (unsigned short*)ws;
  ws += (size_t)NTOK * HDIM * 2;
  unsigned short* act_bf = (unsigned short*)ws;
  ws += (size_t)NEXP * NTOK * IDIM * 2;
  int* cnt = (int*)ws;
  ws += 256;
  int* tok = (int*)ws;
  ws += (size_t)NEXP * NTOK * 4;
  float* wgt = (float*)ws;
  ws += (size_t)NEXP * NTOK * 4;

  hipMemsetAsync(cnt, 0, NEXP * sizeof(int), stream);
  init_out_k<<<2880, 256, 0, stream>>>(x, out);
  rms_router_k<<<NTOK, 256, 0, stream>>>(x, norm_w, gate_w, gate_b, t_bf, cnt,
                                         tok, wgt);
  // x (col-tile) fastest; z row-tile twins are 240 blocks apart = same XCD
  // -> weight re-read is L2-hit.
  gemm1_k<<<dim3(30, NEXP, 4), 512, 0, stream>>>(t_bf, w_gate_up, b_gate_up,
                                                 cnt, tok, act_bf);
  gemm2_k<<<dim3(15, NEXP, 4), 512, 0, stream>>>(act_bf, w_down, b_down, cnt,
                                                 tok, wgt, out);
}